// Round 1
// baseline (458.069 us; speedup 1.0000x reference)
//
#include <hip/hip_runtime.h>
#include <hip/hip_bf16.h>
#include <stdint.h>

#define NTOK 8192
#define DM   1024
#define DH   2048
#define NE   16

// 256x256 tiles: GEMM1 panels = DH/256 = 8, GEMM2 panels = DM/256 = 4.
// Q*MAX = per-XCD queue positions. Fallback (global-order) bounds:
// worst-case totmt <= 80 -> GEMM1 needs 640 slots, GEMM2 320. OK.
#define Q1MAX 128
#define Q2MAX 64
#define GRID1 (8 * Q1MAX)   // 1024
#define GRID2 (8 * Q2MAX)   // 512

typedef float  f32x4  __attribute__((ext_vector_type(4)));
typedef __bf16 bf16x8 __attribute__((ext_vector_type(8)));

__device__ __forceinline__ unsigned short f2bf(float f) {
  union { __bf16 b; unsigned short u; } c; c.b = (__bf16)f; return c.u;
}

__device__ __forceinline__ void glds16(const void* g, void* l) {
  __builtin_amdgcn_global_load_lds(
      (const __attribute__((address_space(1))) void*)g,
      (__attribute__((address_space(3))) void*)l, 16, 0, 0);
}

// ---------------- router: logits, top-2, softmax; also x -> bf16. NO atomics.
__global__ __launch_bounds__(256) void router_kernel(
    const float* __restrict__ x, const float* __restrict__ Wg,
    unsigned short* __restrict__ xb, int* __restrict__ eidx,
    float* __restrict__ ewt)
{
  const int lane = threadIdx.x & 63;
  const int wave = threadIdx.x >> 6;
  const int t = blockIdx.x * 4 + wave;
  const float* xr = x + (size_t)t * DM;

  float4 xv[4];
#pragma unroll
  for (int c = 0; c < 4; ++c)
    xv[c] = *(const float4*)(xr + c * 256 + lane * 4);

  unsigned short* xbr = xb + (size_t)t * DM;
#pragma unroll
  for (int c = 0; c < 4; ++c) {
    ushort4 u;
    u.x = f2bf(xv[c].x); u.y = f2bf(xv[c].y);
    u.z = f2bf(xv[c].z); u.w = f2bf(xv[c].w);
    *(ushort4*)(xbr + c * 256 + lane * 4) = u;
  }

  float acc[NE];
#pragma unroll
  for (int e = 0; e < NE; ++e) acc[e] = 0.f;
#pragma unroll
  for (int e = 0; e < NE; ++e) {
#pragma unroll
    for (int c = 0; c < 4; ++c) {
      float4 wv = *(const float4*)(Wg + e * DM + c * 256 + lane * 4);
      acc[e] += xv[c].x * wv.x + xv[c].y * wv.y + xv[c].z * wv.z + xv[c].w * wv.w;
    }
  }
#pragma unroll
  for (int e = 0; e < NE; ++e) {
    float v = acc[e];
    v += __shfl_xor(v, 1);  v += __shfl_xor(v, 2);  v += __shfl_xor(v, 4);
    v += __shfl_xor(v, 8);  v += __shfl_xor(v, 16); v += __shfl_xor(v, 32);
    acc[e] = v;
  }
  if (lane == 0) {
    float v0 = -1e30f; int i0 = 0;
#pragma unroll
    for (int e = 0; e < NE; ++e) if (acc[e] > v0) { v0 = acc[e]; i0 = e; }
    float v1 = -1e30f; int i1 = 0;
#pragma unroll
    for (int e = 0; e < NE; ++e) if (e != i0 && acc[e] > v1) { v1 = acc[e]; i1 = e; }
    float p = expf(v1 - v0);
    float s = 1.f / (1.f + p);
    eidx[2 * t] = i0; eidx[2 * t + 1] = i1;
    ewt[2 * t] = s;   ewt[2 * t + 1] = p * s;
  }
}

// ---------------- plan: counts, offsets, scatter, XCD-expert-affine queues ---
// XCD x owns experts {x, x+8}. Per-XCD queue: expert-major; panel OUTER,
// m-tile INNER (consecutive blocks share one B panel; A_e stays L2-hot).
// GEMM2 splits each expert's m-range into halves to bound the A slab.
// blockIdx -> slot = pos*8 + xcd (consecutive blockIdx round-robin XCDs).
// Tiles are 256 rows now: nmt = ceil(cnt/256); panels 8 (GEMM1) / 4 (GEMM2).
__global__ __launch_bounds__(1024) void plan_kernel(
    const int* __restrict__ eidx, const float* __restrict__ ewt,
    int* __restrict__ cnt, int* __restrict__ offv,
    int* __restrict__ tok, float* __restrict__ wtl,
    int* __restrict__ wl1, int* __restrict__ wl2)
{
  __shared__ int wcnt[16][NE];
  __shared__ int wbase[16][NE];
  __shared__ int offs[NE];
  __shared__ int s_nmt[NE];
  __shared__ int s_pnmt[NE + 1];
  __shared__ int s_f[2];           // overflow fallback flags

  const int tid  = threadIdx.x;
  const int wave = tid >> 6;
  const int lane = tid & 63;
  const unsigned long long below = (1ull << lane) - 1ull;

  for (int i = tid; i < GRID1; i += 1024) wl1[i] = -1;
  for (int i = tid; i < GRID2; i += 1024) wl2[i] = -1;

  // phase 1: cache pairs; per-wave per-expert counts via ballot
  int   pe[16];
  float pw[16];
  int   count[NE];
#pragma unroll
  for (int e = 0; e < NE; ++e) count[e] = 0;
#pragma unroll
  for (int r = 0; r < 16; ++r) {
    int p = wave * 1024 + r * 64 + lane;
    pe[r] = eidx[p];
    pw[r] = ewt[p];
#pragma unroll
    for (int e = 0; e < NE; ++e) {
      unsigned long long m = __ballot(pe[r] == e);
      count[e] += (int)__popcll(m);
    }
  }
  if (lane == 0) {
#pragma unroll
    for (int e = 0; e < NE; ++e) wcnt[wave][e] = count[e];
  }
  __syncthreads();

  // phase 2: thread 0 serial scan; offsets + tile geometry + overflow check
  if (tid == 0) {
    int s = 0;
    s_pnmt[0] = 0;
    for (int e = 0; e < NE; ++e) {
      offs[e] = s;
      int t = 0;
      for (int w = 0; w < 16; ++w) { wbase[w][e] = t; t += wcnt[w][e]; }
      cnt[e] = t; offv[e] = s; s += t;
      int nmt = (t + 255) >> 8;
      s_nmt[e] = nmt;
      s_pnmt[e + 1] = s_pnmt[e] + nmt;
    }
    offv[NE] = s;
    int f1 = 0, f2 = 0;
    for (int x = 0; x < 8; ++x) {
      int pmt = s_nmt[x] + s_nmt[x + 8];
      if (pmt * 8 > Q1MAX) f1 = 1;
      if (pmt * 4 > Q2MAX) f2 = 1;
    }
    s_f[0] = f1; s_f[1] = f2;
  }
  __syncthreads();

  // phase 2b: parallel worklist fill (closed-form positions)
  {
    const int totmt = s_pnmt[NE];
    const int f1 = s_f[0], f2 = s_f[1];
    const int T1 = totmt * 8;
    for (int i = tid; i < T1; i += 1024) {
      int gmt = i >> 3, p = i & 7;
      int e = 0;
      while (s_pnmt[e + 1] <= gmt) ++e;
      int mt  = gmt - s_pnmt[e];
      int nmt = s_nmt[e];
      int slot;
      if (!f1) {
        int x    = e & 7;
        int base = (e < 8) ? 0 : s_nmt[e - 8] * 8;
        int pos  = base + p * nmt + mt;
        slot = pos * 8 + x;
      } else {
        slot = s_pnmt[e] * 8 + p * nmt + mt;   // global order fallback
      }
      wl1[slot] = (e << 16) | (mt << 8) | p;
    }
    const int T2 = totmt * 4;
    for (int i = tid; i < T2; i += 1024) {
      int gmt = i >> 2, p = i & 3;
      int e = 0;
      while (s_pnmt[e + 1] <= gmt) ++e;
      int mt  = gmt - s_pnmt[e];
      int nmt = s_nmt[e];
      int h0  = (nmt + 1) >> 1;
      int pos_e = (mt < h0) ? (p * h0 + mt)
                            : (h0 * 4 + p * (nmt - h0) + (mt - h0));
      int slot;
      if (!f2) {
        int x    = e & 7;
        int base = (e < 8) ? 0 : s_nmt[e - 8] * 4;
        slot = (base + pos_e) * 8 + x;
      } else {
        slot = s_pnmt[e] * 4 + pos_e;
      }
      wl2[slot] = (e << 16) | (mt << 8) | p;
    }
  }

  // phase 3: rank + scatter tokens (deterministic)
  int run[NE];
#pragma unroll
  for (int e = 0; e < NE; ++e) run[e] = 0;
#pragma unroll
  for (int r = 0; r < 16; ++r) {
    int p = wave * 1024 + r * 64 + lane;
#pragma unroll
    for (int e = 0; e < NE; ++e) {
      unsigned long long m = __ballot(pe[r] == e);
      if (pe[r] == e) {
        int rank = (int)__popcll(m & below);
        int slot = offs[e] + wbase[wave][e] + run[e] + rank;
        tok[slot] = p >> 1;
        wtl[slot] = pw[r];
      }
      run[e] += (int)__popcll(m);
    }
  }
}

// ---------------- weight prep: fp32 [E][K][N] -> bf16 [E][N][K] -------------
__global__ __launch_bounds__(256) void wprep_kernel(
    const float* __restrict__ W, unsigned short* __restrict__ WT,
    int K, int N)
{
  __shared__ float t[64][68];
  const int e = blockIdx.z;
  const int k0 = blockIdx.y * 64;
  const int n0 = blockIdx.x * 64;
  const int tid = threadIdx.x;
  const int tr = tid >> 2;
  const int tc = (tid & 3) * 16;
  const float* src = W + ((size_t)e * K + k0) * N + n0;
#pragma unroll
  for (int j = 0; j < 4; ++j) {
    float4 v = *(const float4*)(src + (size_t)tr * N + tc + j * 4);
    t[tc + j * 4 + 0][tr] = v.x;
    t[tc + j * 4 + 1][tr] = v.y;
    t[tc + j * 4 + 2][tr] = v.z;
    t[tc + j * 4 + 3][tr] = v.w;
  }
  __syncthreads();
  unsigned short* dst = WT + ((size_t)e * N + n0) * K + k0;
#pragma unroll
  for (int j = 0; j < 4; ++j) {
    float4 v = *(const float4*)(&t[tr][tc + j * 4]);
    ushort4 u;
    u.x = f2bf(v.x); u.y = f2bf(v.y); u.z = f2bf(v.z); u.w = f2bf(v.w);
    *(ushort4*)(dst + (size_t)tr * K + tc + j * 4) = u;
  }
}

// ---------------- 256x256 gathered GEMM, BK=64, 8 waves, 2-phase dbuf -------
// T3 minimal 2-phase: STAGE tile t+1 into buf^1 BEFORE computing tile t;
// one __syncthreads per tile (its implicit vmcnt(0)+lgkmcnt(0) drain lands
// AFTER the compute phase, so the prefetch latency hides under 64 MFMAs).
// XOR k-chunk swizzle (source-side pre-swizzle, read-side ch^swz) kept from
// the verified 128^2 kernel -> 2-way LDS aliasing only (free).
// EPI=0: h = relu(acc+b1) -> bf16    EPI=1: atomicAdd(out, (acc+b2)*w)
template<int GATHER, int EPI, int KDIM, int NDIM>
__global__ __launch_bounds__(512, 2) void gemm_kernel(
    const unsigned short* __restrict__ Abase,
    const unsigned short* __restrict__ BT,
    const float* __restrict__ bias,
    const int* __restrict__ cnt, const int* __restrict__ offv,
    const int* __restrict__ tok, const float* __restrict__ wtl,
    const int* __restrict__ wl, void* __restrict__ outp)
{
  const int v = wl[blockIdx.x];
  if (v < 0) return;
  const int e  = (v >> 16) & 0xff;
  const int m0 = ((v >> 8) & 0xff) * 256;
  const int n0 = (v & 0xff) * 256;
  const int count = cnt[e];
  const int o     = offv[e];

  __shared__ unsigned short Al[2][256 * 64];   // 2 x 32 KB
  __shared__ unsigned short Bl[2][256 * 64];   // 2 x 32 KB  -> 128 KB total

  const int tid  = threadIdx.x;
  const int lane = tid & 63;
  const int wave = tid >> 6;
  const int wr = wave >> 2;        // 0..1  (M half)
  const int wc = wave & 3;         // 0..3  (N quarter)

  const int lr = lane >> 3;        // row within 8-row group
  const int lc = lane & 7;         // k-chunk slot
  const int sc = (lc ^ lr) * 8;    // inverse-swizzled source k-offset
  const unsigned short* aptr[4];
  const unsigned short* bptr[4];
#pragma unroll
  for (int ii = 0; ii < 4; ++ii) {
    int r = ii * 64 + wave * 8 + lr;       // covers all 256 tile rows
    int m = m0 + r; if (m > count - 1) m = count - 1;
    size_t arow = GATHER ? (size_t)tok[o + m] : (size_t)(o + m);
    aptr[ii] = Abase + arow * KDIM + sc;
    bptr[ii] = BT + ((size_t)e * NDIM + n0 + r) * KDIM + sc;
  }

  f32x4 acc[8][4];
#pragma unroll
  for (int a = 0; a < 8; ++a)
#pragma unroll
    for (int b = 0; b < 4; ++b) acc[a][b] = 0.f;

  const int q    = lane >> 4;
  const int ln15 = lane & 15;
  const int swz  = ln15 & 7;

  constexpr int NT = KDIM / 64;

  // prologue: stage tile 0 into buf 0, drain, enter steady state
#pragma unroll
  for (int ii = 0; ii < 4; ++ii) {
    int ro = (ii * 64 + wave * 8) * 64;
    glds16(aptr[ii], &Al[0][ro]);
    glds16(bptr[ii], &Bl[0][ro]);
  }
  __syncthreads();

#define KSTEP(CUR, T)                                                         \
  {                                                                           \
    if ((T) + 1 < NT) {                                                       \
      const int k0 = ((T) + 1) * 64;                                          \
      _Pragma("unroll")                                                       \
      for (int ii = 0; ii < 4; ++ii) {                                        \
        int ro = (ii * 64 + wave * 8) * 64;                                   \
        glds16(aptr[ii] + k0, &Al[(CUR) ^ 1][ro]);                            \
        glds16(bptr[ii] + k0, &Bl[(CUR) ^ 1][ro]);                            \
      }                                                                       \
    }                                                                         \
    _Pragma("unroll")                                                         \
    for (int kk = 0; kk < 2; ++kk) {                                          \
      bf16x8 af[8], bg[4];                                                    \
      const int ch = ((kk * 4 + q) ^ swz) * 8;                                \
      _Pragma("unroll")                                                       \
      for (int a = 0; a < 8; ++a)                                             \
        af[a] = *(const bf16x8*)(&Al[CUR][(wr * 128 + a * 16 + ln15) * 64 + ch]); \
      _Pragma("unroll")                                                       \
      for (int b = 0; b < 4; ++b)                                             \
        bg[b] = *(const bf16x8*)(&Bl[CUR][(wc * 64 + b * 16 + ln15) * 64 + ch]);  \
      _Pragma("unroll")                                                       \
      for (int a = 0; a < 8; ++a)                                             \
        _Pragma("unroll")                                                     \
        for (int b = 0; b < 4; ++b)                                           \
          acc[a][b] = __builtin_amdgcn_mfma_f32_16x16x32_bf16(af[a], bg[b], acc[a][b], 0, 0, 0); \
    }                                                                         \
    __syncthreads();                                                          \
  }

  for (int t = 0; t < NT; t += 2) {
    KSTEP(0, t)
    KSTEP(1, t + 1)
  }
#undef KSTEP

  float bn[4];
#pragma unroll
  for (int b = 0; b < 4; ++b)
    bn[b] = bias[(size_t)e * NDIM + n0 + wc * 64 + b * 16 + ln15];

  if (EPI == 0) {
    unsigned short* hout = (unsigned short*)outp;
#pragma unroll
    for (int a = 0; a < 8; ++a)
#pragma unroll
      for (int rg = 0; rg < 4; ++rg) {
        int m = m0 + wr * 128 + a * 16 + q * 4 + rg;
        if (m < count) {
          size_t slot = (size_t)(o + m);
#pragma unroll
          for (int b = 0; b < 4; ++b) {
            float v2 = acc[a][b][rg] + bn[b];
            v2 = v2 > 0.f ? v2 : 0.f;
            hout[slot * NDIM + n0 + wc * 64 + b * 16 + ln15] = f2bf(v2);
          }
        }
      }
  } else {
    float* obase = (float*)outp;
#pragma unroll
    for (int a = 0; a < 8; ++a)
#pragma unroll
      for (int rg = 0; rg < 4; ++rg) {
        int m = m0 + wr * 128 + a * 16 + q * 4 + rg;
        if (m < count) {
          int slot = o + m;
          int tk = tok[slot];
          float w = wtl[slot];
#pragma unroll
          for (int b = 0; b < 4; ++b) {
            float v2 = (acc[a][b][rg] + bn[b]) * w;
            atomicAdd(&obase[(size_t)tk * NDIM + n0 + wc * 64 + b * 16 + ln15], v2);
          }
        }
      }
  }
}

// ---------------- launch ----------------------------------------------------
extern "C" void kernel_launch(void* const* d_in, const int* in_sizes, int n_in,
                              void* d_out, int out_size, void* d_ws, size_t ws_size,
                              hipStream_t stream) {
  const float* x  = (const float*)d_in[0];
  const float* Wg = (const float*)d_in[1];
  const float* W1 = (const float*)d_in[2];
  const float* b1 = (const float*)d_in[3];
  const float* W2 = (const float*)d_in[4];
  const float* b2 = (const float*)d_in[5];

  constexpr size_t OFF_CNT  = 0;
  constexpr size_t OFF_OFF  = 256;
  constexpr size_t OFF_WL1  = 4096;
  constexpr size_t OFF_WL2  = OFF_WL1 + (size_t)GRID1 * 4;
  constexpr size_t OFF_EIDX = 131072;
  constexpr size_t OFF_EWT  = OFF_EIDX + (size_t)NTOK * 2 * 4;
  constexpr size_t OFF_TOK  = OFF_EWT  + (size_t)NTOK * 2 * 4;
  constexpr size_t OFF_WTL  = OFF_TOK  + (size_t)NTOK * 2 * 4;
  constexpr size_t OFF_XB   = (size_t)1 << 20;
  constexpr size_t OFF_W1T  = OFF_XB  + (size_t)NTOK * DM * 2;
  constexpr size_t OFF_W2T  = OFF_W1T + (size_t)NE * DM * DH * 2;
  constexpr size_t OFF_H    = OFF_W2T + (size_t)NE * DH * DM * 2;
  constexpr size_t REQ      = OFF_H   + (size_t)NTOK * 2 * DH * 2;

  if (ws_size < REQ) {
    hipMemsetAsync(d_out, 0, (size_t)out_size * 4, stream);
    return;
  }

  char* ws = (char*)d_ws;
  int*   cnt    = (int*)(ws + OFF_CNT);
  int*   offv   = (int*)(ws + OFF_OFF);
  int*   wl1    = (int*)(ws + OFF_WL1);
  int*   wl2    = (int*)(ws + OFF_WL2);
  int*   eidx   = (int*)(ws + OFF_EIDX);
  float* ewt    = (float*)(ws + OFF_EWT);
  int*   tok    = (int*)(ws + OFF_TOK);
  float* wtl    = (float*)(ws + OFF_WTL);
  unsigned short* xb   = (unsigned short*)(ws + OFF_XB);
  unsigned short* w1t  = (unsigned short*)(ws + OFF_W1T);
  unsigned short* w2t  = (unsigned short*)(ws + OFF_W2T);
  unsigned short* hbuf = (unsigned short*)(ws + OFF_H);

  hipMemsetAsync(d_out, 0, (size_t)out_size * 4, stream);   // atomic target

  router_kernel<<<NTOK / 4, 256, 0, stream>>>(x, Wg, xb, eidx, ewt);
  wprep_kernel<<<dim3(DH / 64, DM / 64, NE), 256, 0, stream>>>(W1, w1t, DM, DH);
  wprep_kernel<<<dim3(DM / 64, DH / 64, NE), 256, 0, stream>>>(W2, w2t, DH, DM);
  plan_kernel<<<1, 1024, 0, stream>>>(eidx, ewt, cnt, offv, tok, wtl, wl1, wl2);

  // GEMM1: h = relu(x @ W1 + b1), gathered rows, K=1024, N=2048
  gemm_kernel<1, 0, DM, DH><<<GRID1, 512, 0, stream>>>(
      xb, w1t, b1, cnt, offv, tok, wtl, wl1, hbuf);
  // GEMM2: out[tok] += (h @ W2 + b2) * w, K=2048, N=1024
  gemm_kernel<0, 1, DH, DM><<<GRID2, 512, 0, stream>>>(
      hbuf, w2t, b2, cnt, offv, tok, wtl, wl2, (float*)d_out);
}